// Round 1
// baseline (686.084 us; speedup 1.0000x reference)
//
#include <hip/hip_runtime.h>
#include <hip/hip_bf16.h>

#define N_NODES 100000
#define N_HEDGES 100000
#define N_INC 1600000
#define D 128

#define B_KEYS 512            // keys per bucket
#define NBUCK 196             // ceil(100000/512)
#define CAP 10240             // bucket capacity (mean 8192, sigma ~90)
#define CHUNK 4096            // 16 items per thread, register-resident
#define NBLKA ((N_INC + CHUNK - 1) / CHUNK)   // 391

#define LDA 136               // padded bf16 row stride for GEMM LDS tiles

// ---- feature-sliced planar layout: 8 planes of 16 features (32 B) ----
// plane s is a contiguous 3.2 MB region -> L2-resident on the XCD that owns
// slice s (blockIdx & 7 ~ XCD round-robin). Kills the 8x-XCD L2-fill floor.
#define NSLICE 8
#define PLANE_SHORTS ((size_t)N_NODES * 16)
#define PLANE_BYTES  ((size_t)N_NODES * 32)
#define GSLICE 2048           // blocks per slice in agg kernels

typedef __attribute__((ext_vector_type(8))) short bf16x8;
typedef __attribute__((ext_vector_type(4))) float f32x4;

__device__ __forceinline__ short f2bf(float v) {
    __hip_bfloat16 b = __float2bfloat16(v);
    return *(short*)&b;
}
__device__ __forceinline__ unsigned packbf2(float x, float y) {
    __hip_bfloat162 p = __float22bfloat162_rn(make_float2(x, y));
    return *(unsigned*)&p;
}

// ---------------- W transpose + bf16 convert (once per call) ----------------
// also zeroes the gcnt counter block (block 0) so no memset dispatch is needed
__global__ void wt_kernel(const float* __restrict__ W1, const float* __restrict__ W2,
                          short* __restrict__ WT1, short* __restrict__ WT2,
                          int* __restrict__ gcnt) {
    if (blockIdx.x == 0) {
        for (int i = threadIdx.x; i < 2 * NBUCK; i += 256) gcnt[i] = 0;
    }
    int idx = blockIdx.x * 256 + threadIdx.x;     // 0..32767
    int sel = idx >> 14;
    int li = idx & 16383;
    int n = li >> 7, k = li & 127;
    const float* src = sel ? W2 : W1;
    short* dst = sel ? WT2 : WT1;
    dst[li] = f2bf(src[k * 128 + n]);
}

// ---------------- Phase A: bucket partition, register-resident chunk ----------------
__launch_bounds__(256)
__global__ void binA_kernel(const int* __restrict__ nidx, const int* __restrict__ hidx,
                            int* __restrict__ gcnt_e, int* __restrict__ gcnt_n,
                            unsigned* __restrict__ bin_e, unsigned* __restrict__ bin_n) {
    __shared__ int hist_e[NBUCK], hist_n[NBUCK], base_e[NBUCK], base_n[NBUCK];
    int t = threadIdx.x;
    int items_h[16], items_n[16];
    int start = blockIdx.x * CHUNK;
#pragma unroll
    for (int k = 0; k < 16; ++k) {
        int i = start + t + k * 256;
        bool ok = i < N_INC;
        items_h[k] = ok ? hidx[i] : -1;
        items_n[k] = ok ? nidx[i] : -1;
    }
    for (int b = t; b < NBUCK; b += 256) { hist_e[b] = 0; hist_n[b] = 0; }
    __syncthreads();
#pragma unroll
    for (int k = 0; k < 16; ++k) {
        if (items_h[k] >= 0) {
            atomicAdd(&hist_e[items_h[k] >> 9], 1);
            atomicAdd(&hist_n[items_n[k] >> 9], 1);
        }
    }
    __syncthreads();
    for (int b = t; b < NBUCK; b += 256) {
        base_e[b] = atomicAdd(&gcnt_e[b], hist_e[b]);
        base_n[b] = atomicAdd(&gcnt_n[b], hist_n[b]);
        hist_e[b] = 0; hist_n[b] = 0;
    }
    __syncthreads();
#pragma unroll
    for (int k = 0; k < 16; ++k) {
        if (items_h[k] >= 0) {
            int h = items_h[k], n = items_n[k];
            int be = h >> 9, bn = n >> 9;
            int oe = base_e[be] + atomicAdd(&hist_e[be], 1);
            if (oe >= 0 && oe < CAP) bin_e[(size_t)be * CAP + oe] = ((unsigned)(h & 511) << 17) | (unsigned)n;
            int on = base_n[bn] + atomicAdd(&hist_n[bn], 1);
            if (on >= 0 && on < CAP) bin_n[(size_t)bn * CAP + on] = ((unsigned)(n & 511) << 17) | (unsigned)h;
        }
    }
}

// ---------------- Phase B: per-bucket counting sort, wave-shuffle scan ----------
// seg meta packed as int2 (start, cnt); scale is recomputed in the agg kernels.
__launch_bounds__(512)
__global__ void binB2_kernel(const int* __restrict__ gcnt_e, const unsigned* __restrict__ bin_e,
                             int* __restrict__ csr_e, int2* __restrict__ meta_e,
                             const int* __restrict__ gcnt_n, const unsigned* __restrict__ bin_n,
                             int* __restrict__ csr_n, int2* __restrict__ meta_n) {
    __shared__ int kc[B_KEYS];
    __shared__ int wsum[8];
    int b = blockIdx.x;
    const int* gcnt;  const unsigned* bin;  int* csr;  int2* meta;
    if (b < NBUCK) { gcnt = gcnt_e; bin = bin_e; csr = csr_e; meta = meta_e; }
    else { b -= NBUCK; gcnt = gcnt_n; bin = bin_n; csr = csr_n; meta = meta_n; }
    int t = threadIdx.x;
    int lane = t & 63, wv = t >> 6;
    int cnt = gcnt[b];
    if (cnt > CAP) cnt = CAP;
    kc[t] = 0;
    __syncthreads();
    const unsigned* items = bin + (size_t)b * CAP;
    for (int i = t; i < cnt; i += 512) atomicAdd(&kc[items[i] >> 17], 1);
    __syncthreads();
    int mycnt = kc[t];
    int v = mycnt;
#pragma unroll
    for (int off = 1; off < 64; off <<= 1) {
        int u = __shfl_up(v, off);
        if (lane >= off) v += u;
    }
    if (lane == 63) wsum[wv] = v;
    __syncthreads();
    int addp = 0;
#pragma unroll
    for (int w = 0; w < 7; ++w) addp += (w < wv) ? wsum[w] : 0;
    int incl = v + addp;
    int sstart = b * CAP + (incl - mycnt);   // exclusive start
    meta[b * B_KEYS + t] = make_int2(sstart, mycnt);
    kc[t] = sstart;
    __syncthreads();
    for (int i = t; i < cnt; i += 512) {
        unsigned it = items[i];
        int pos = atomicAdd(&kc[it >> 17], 1);
        csr[pos] = (int)(it & 0x1FFFFu);
    }
}

// ---------------- MFMA bf16 GEMM: planar output [8][N][16 feats] ----------------
// PLANAR=false: X is fp32 row-major [N][128]; PLANAR=true: X is bf16 planar.
template <bool PLANAR>
__launch_bounds__(256)
__global__ void gemm_mfma_kernel(const void* __restrict__ Xv, const short* __restrict__ WT,
                                 char* __restrict__ Y, int nrows) {
    __shared__ short lds_w[128 * LDA];   // W^T [n][k]; later reused for C staging
    int tid = threadIdx.x;
    int row0 = blockIdx.x * 64;

    {
        const uint4* w4 = (const uint4*)WT;
#pragma unroll
        for (int i = 0; i < 8; ++i) {
            int idx = tid + i * 256;          // 0..2047 = 128 rows x 16 uint4
            int n = idx >> 4, g = idx & 15;
            *(uint4*)(lds_w + n * LDA + g * 8) = w4[idx];
        }
    }

    int wv = tid >> 6, lane = tid & 63;
    int m = lane & 15, quad = lane >> 4;
    int row = row0 + wv * 16 + m;
    bool rowok = row < nrows;

    bf16x8 af[4];
    if constexpr (!PLANAR) {
        const float* xr = (const float*)Xv + (size_t)row * 128 + quad * 8;
#pragma unroll
        for (int k0 = 0; k0 < 4; ++k0) {
            float4 a0 = make_float4(0.f, 0.f, 0.f, 0.f), a1 = a0;
            if (rowok) {
                a0 = *(const float4*)(xr + k0 * 32);
                a1 = *(const float4*)(xr + k0 * 32 + 4);
            }
            bf16x8 f;
            f[0] = f2bf(a0.x); f[1] = f2bf(a0.y); f[2] = f2bf(a0.z); f[3] = f2bf(a0.w);
            f[4] = f2bf(a1.x); f[5] = f2bf(a1.y); f[6] = f2bf(a1.z); f[7] = f2bf(a1.w);
            af[k0] = f;
        }
    } else {
        const short* X = (const short*)Xv;
#pragma unroll
        for (int k0 = 0; k0 < 4; ++k0) {
            // features k0*32 + quad*8 .. +8 live in plane k0*2 + (quad>>1),
            // within-slice offset (quad&1)*8 shorts
            int p = k0 * 2 + (quad >> 1);
            bf16x8 f = {0, 0, 0, 0, 0, 0, 0, 0};
            if (rowok) f = *(const bf16x8*)(X + (size_t)p * PLANE_SHORTS + (size_t)row * 16 + (quad & 1) * 8);
            af[k0] = f;
        }
    }
    __syncthreads();   // W staged

    f32x4 zero = {0.f, 0.f, 0.f, 0.f};
    f32x4 acc[8];
#pragma unroll
    for (int t8 = 0; t8 < 8; ++t8) acc[t8] = zero;

#pragma unroll
    for (int t8 = 0; t8 < 8; ++t8) {
        const short* brow = lds_w + (t8 * 16 + m) * LDA + quad * 8;
#pragma unroll
        for (int k0 = 0; k0 < 4; ++k0) {
            bf16x8 bf = *(const bf16x8*)(brow + k0 * 32);
            acc[t8] = __builtin_amdgcn_mfma_f32_16x16x32_bf16(af[k0], bf, acc[t8], 0, 0, 0);
        }
    }

    __syncthreads();   // all W ds_reads done; reuse lds_w for C staging
    // C/D layout: col = lane&15, row = quad*4 + reg
#pragma unroll
    for (int t8 = 0; t8 < 8; ++t8) {
#pragma unroll
        for (int r = 0; r < 4; ++r) {
            int crow = wv * 16 + quad * 4 + r;
            int col = t8 * 16 + m;
            lds_w[crow * LDA + col] = f2bf(acc[t8][r]);
        }
    }
    __syncthreads();
    // planar store: per wave one plane, 64 rows x 2 halves = 1 KB contiguous
#pragma unroll
    for (int i = 0; i < 4; ++i) {
        int idx = tid + i * 256;              // 0..1023
        int slice = idx >> 7, j = idx & 127;  // j = row*2 + half
        int r = j >> 1, h = j & 1;
        if (row0 + r < nrows) {
            uint4 u = *(const uint4*)(lds_w + r * LDA + slice * 16 + h * 8);
            *(uint4*)(Y + (size_t)slice * PLANE_BYTES + (size_t)(row0 + r) * 32 + h * 16) = u;
        }
    }
}

// ---------------- sliced segment gather-sum ----------------
__device__ __forceinline__ void acc8_add(float* a, uint4 u) {
    a[0] += __uint_as_float(u.x << 16); a[1] += __uint_as_float(u.x & 0xFFFF0000u);
    a[2] += __uint_as_float(u.y << 16); a[3] += __uint_as_float(u.y & 0xFFFF0000u);
    a[4] += __uint_as_float(u.z << 16); a[5] += __uint_as_float(u.z & 0xFFFF0000u);
    a[6] += __uint_as_float(u.w << 16); a[7] += __uint_as_float(u.w & 0xFFFF0000u);
}
__device__ __forceinline__ void acc8_fma(float* a, uint4 u, float msk) {
    a[0] = fmaf(msk, __uint_as_float(u.x << 16), a[0]);
    a[1] = fmaf(msk, __uint_as_float(u.x & 0xFFFF0000u), a[1]);
    a[2] = fmaf(msk, __uint_as_float(u.y << 16), a[2]);
    a[3] = fmaf(msk, __uint_as_float(u.y & 0xFFFF0000u), a[3]);
    a[4] = fmaf(msk, __uint_as_float(u.z << 16), a[4]);
    a[5] = fmaf(msk, __uint_as_float(u.z & 0xFFFF0000u), a[5]);
    a[6] = fmaf(msk, __uint_as_float(u.w << 16), a[6]);
    a[7] = fmaf(msk, __uint_as_float(u.w & 0xFFFF0000u), a[7]);
}

// MODE 0: edge agg (scale only, planar bf16 out)
// MODE 1: node agg + bias + relu (planar bf16 out)
// MODE 2: node agg + bias + relu -> per-block column partials (dst = float*)
// slice = blockIdx & 7 -> XCD round-robin; each XCD gathers only from its own
// 3.2 MB plane (L2-resident). Index/meta streams loaded nontemporal so they
// don't evict the plane.
template <int MODE>
__launch_bounds__(256)
__global__ void agg_planar_kernel(const char* __restrict__ src, const int2* __restrict__ meta,
                                  const int* __restrict__ col, const float* __restrict__ bias,
                                  char* __restrict__ dst) {
    int slice = blockIdx.x & 7;
    int g = blockIdx.x >> 3;
    int tid = threadIdx.x;
    int wid = tid >> 6, lane = tid & 63;
    int sub = lane >> 4;            // segment within wave (4 segs/wave)
    int slot = (lane >> 1) & 7;     // 8 gather rows in flight per segment
    int half = lane & 1;            // which 16 B half of the 32 B slice row
    const char* plane = src + (size_t)slice * PLANE_BYTES;
    const int* mp = (const int*)meta;

    float b8[8];
    if constexpr (MODE >= 1) {
        const float4* b4 = (const float4*)(bias + slice * 16 + half * 8);
        float4 lo = b4[0], hi = b4[1];
        b8[0] = lo.x; b8[1] = lo.y; b8[2] = lo.z; b8[3] = lo.w;
        b8[4] = hi.x; b8[5] = hi.y; b8[6] = hi.z; b8[7] = hi.w;
    }
    float psum[8];
    if constexpr (MODE == 2) {
#pragma unroll
        for (int i = 0; i < 8; ++i) psum[i] = 0.f;
    }

    for (int sb = g * 16 + wid * 4; sb < N_NODES; sb += GSLICE * 16) {
        int seg = sb + sub;
        int s   = __builtin_nontemporal_load(mp + seg * 2);
        int cnt = __builtin_nontemporal_load(mp + seg * 2 + 1);
        int e = s + cnt;
        float acc[8] = {0.f, 0.f, 0.f, 0.f, 0.f, 0.f, 0.f, 0.f};
        int base = s;
        int nb = cnt >> 3;
        for (int bb = 0; bb < nb; ++bb, base += 8) {
            int idx = __builtin_nontemporal_load(col + base + slot);
            uint4 u = *(const uint4*)(plane + (size_t)idx * 32 + half * 16);
            acc8_add(acc, u);
        }
        if (cnt & 7) {                       // masked tail batch
            int j = base + slot;
            float msk = (j < e) ? 1.0f : 0.0f;
            int jc = (j < e) ? j : s;
            int idx = __builtin_nontemporal_load(col + jc);
            uint4 u = *(const uint4*)(plane + (size_t)idx * 32 + half * 16);
            acc8_fma(acc, u, msk);
        }
        // reduce across the 8 row slots (lane bits 1..3)
#pragma unroll
        for (int i = 0; i < 8; ++i) {
            acc[i] += __shfl_xor(acc[i], 2);
            acc[i] += __shfl_xor(acc[i], 4);
            acc[i] += __shfl_xor(acc[i], 8);
        }
        if (slot == 0) {
            float sc = cnt ? 1.0f / (float)cnt : 0.0f;
            if constexpr (MODE == 0) {
                uint4 o;
                o.x = packbf2(acc[0] * sc, acc[1] * sc);
                o.y = packbf2(acc[2] * sc, acc[3] * sc);
                o.z = packbf2(acc[4] * sc, acc[5] * sc);
                o.w = packbf2(acc[6] * sc, acc[7] * sc);
                *(uint4*)(dst + (size_t)slice * PLANE_BYTES + (size_t)seg * 32 + half * 16) = o;
            } else if constexpr (MODE == 1) {
                uint4 o;
                o.x = packbf2(fmaxf(fmaf(acc[0], sc, b8[0]), 0.f), fmaxf(fmaf(acc[1], sc, b8[1]), 0.f));
                o.y = packbf2(fmaxf(fmaf(acc[2], sc, b8[2]), 0.f), fmaxf(fmaf(acc[3], sc, b8[3]), 0.f));
                o.z = packbf2(fmaxf(fmaf(acc[4], sc, b8[4]), 0.f), fmaxf(fmaf(acc[5], sc, b8[5]), 0.f));
                o.w = packbf2(fmaxf(fmaf(acc[6], sc, b8[6]), 0.f), fmaxf(fmaf(acc[7], sc, b8[7]), 0.f));
                *(uint4*)(dst + (size_t)slice * PLANE_BYTES + (size_t)seg * 32 + half * 16) = o;
            } else {
#pragma unroll
                for (int i = 0; i < 8; ++i)
                    psum[i] += fmaxf(fmaf(acc[i], sc, b8[i]), 0.f);
            }
        }
    }
    if constexpr (MODE == 2) {
        __shared__ float sp[16];
        if (tid < 16) sp[tid] = 0.f;
        __syncthreads();
        if (slot == 0) {
#pragma unroll
            for (int i = 0; i < 8; ++i) atomicAdd(&sp[half * 8 + i], psum[i]);
        }
        __syncthreads();
        if (tid < 16)
            ((float*)dst)[((size_t)slice * GSLICE + g) * 16 + tid] = sp[tid];
    }
}

// ---------------- mean: reduce per-block partials [8][GSLICE][16] ----------------
__launch_bounds__(256)
__global__ void mean_kernel(const float* __restrict__ partials, float* __restrict__ out) {
    __shared__ float sd[256];
    int f = blockIdx.x;               // 0..127
    int slice = f >> 4, w = f & 15;
    float s = 0.f;
    for (int g = threadIdx.x; g < GSLICE; g += 256)
        s += partials[((size_t)slice * GSLICE + g) * 16 + w];
    sd[threadIdx.x] = s;
    __syncthreads();
#pragma unroll
    for (int o = 128; o > 0; o >>= 1) {
        if (threadIdx.x < o) sd[threadIdx.x] += sd[threadIdx.x + o];
        __syncthreads();
    }
    if (threadIdx.x == 0) out[f] = sd[0] * (1.0f / (float)N_NODES);
}

// ---------------- launch ----------------
extern "C" void kernel_launch(void* const* d_in, const int* in_sizes, int n_in,
                              void* d_out, int out_size, void* d_ws, size_t ws_size,
                              hipStream_t stream) {
    const float* x  = (const float*)d_in[0];
    const int*   ei = (const int*)d_in[1];
    const float* w1 = (const float*)d_in[2];
    const float* b1 = (const float*)d_in[3];
    const float* w2 = (const float*)d_in[4];
    const float* b2 = (const float*)d_in[5];
    float* out = (float*)d_out;
    const int* nidx = ei;
    const int* hidx = ei + N_INC;

    char* wsp = (char*)d_ws;
    size_t off = 0;
    auto alloc = [&](size_t bytes) -> void* {
        void* p = wsp + off;
        off += (bytes + 255) & ~(size_t)255;
        return p;
    };

    char* B0         = (char*)alloc((size_t)N_NODES * 128 * 2);   // planar bf16
    char* B1         = (char*)alloc((size_t)N_NODES * 128 * 2);   // planar bf16
    unsigned* bin_e  = (unsigned*)alloc((size_t)NBUCK * CAP * 4);
    unsigned* bin_n  = (unsigned*)alloc((size_t)NBUCK * CAP * 4);
    int* csr_e       = (int*)alloc((size_t)NBUCK * CAP * 4);
    int* csr_n       = (int*)alloc((size_t)NBUCK * CAP * 4);
    float* partials  = (float*)alloc((size_t)NSLICE * GSLICE * 16 * 4);
    int2* meta_e     = (int2*)alloc((size_t)NBUCK * B_KEYS * 8);
    int2* meta_n     = (int2*)alloc((size_t)NBUCK * B_KEYS * 8);
    short* WT1       = (short*)alloc((size_t)128 * 128 * 2);
    short* WT2       = (short*)alloc((size_t)128 * 128 * 2);
    int* gcnt        = (int*)alloc((size_t)2 * NBUCK * 4);
    int* gcnt_e = gcnt;
    int* gcnt_n = gcnt + NBUCK;

    wt_kernel<<<128, 256, 0, stream>>>(w1, w2, WT1, WT2, gcnt);
    binA_kernel<<<NBLKA, 256, 0, stream>>>(nidx, hidx, gcnt_e, gcnt_n, bin_e, bin_n);
    binB2_kernel<<<2 * NBUCK, 512, 0, stream>>>(gcnt_e, bin_e, csr_e, meta_e,
                                                gcnt_n, bin_n, csr_n, meta_n);

    int gGemm = (N_NODES + 63) / 64;
    int gAgg = NSLICE * GSLICE;

    // layer 1
    gemm_mfma_kernel<false><<<gGemm, 256, 0, stream>>>(x, WT1, B0, N_NODES);
    agg_planar_kernel<0><<<gAgg, 256, 0, stream>>>(B0, meta_e, csr_e, nullptr, B1);
    agg_planar_kernel<1><<<gAgg, 256, 0, stream>>>(B1, meta_n, csr_n, b1, B0);
    // layer 2
    gemm_mfma_kernel<true><<<gGemm, 256, 0, stream>>>(B0, WT2, B1, N_NODES);
    agg_planar_kernel<0><<<gAgg, 256, 0, stream>>>(B1, meta_e, csr_e, nullptr, B0);
    agg_planar_kernel<2><<<gAgg, 256, 0, stream>>>(B0, meta_n, csr_n, b2, (char*)partials);
    mean_kernel<<<128, 256, 0, stream>>>(partials, out);
}

// Round 2
// 522.095 us; speedup vs baseline: 1.3141x; 1.3141x over previous
//
#include <hip/hip_runtime.h>
#include <hip/hip_bf16.h>

#define N_NODES 100000
#define N_HEDGES 100000
#define N_INC 1600000
#define D 128

#define B_KEYS 512            // keys per bucket
#define NBUCK 196             // ceil(100000/512)
#define CAP 10240             // bucket capacity (mean 8192, sigma ~90)
#define CHUNK 4096            // 16 items per thread, register-resident
#define NBLKA ((N_INC + CHUNK - 1) / CHUNK)   // 391

#define LDA 136               // padded bf16 row stride for GEMM LDS tiles

// ---- feature-sliced planar layout: 8 planes of 16 features (32 B) ----
// plane s is a contiguous 3.2 MB region -> L2-resident on the XCD that owns
// slice s (blockIdx & 7 ~ XCD round-robin). Round-1 proof: FETCH_SIZE dropped
// 181 MB -> 52 MB (= index stream only), planes fully L2-resident.
#define NSLICE 8
#define PLANE_SHORTS ((size_t)N_NODES * 16)
#define PLANE_BYTES  ((size_t)N_NODES * 32)
#define GSLICE 2048           // blocks per slice in agg kernels

typedef __attribute__((ext_vector_type(8))) short bf16x8;
typedef __attribute__((ext_vector_type(4))) float f32x4;

__device__ __forceinline__ short f2bf(float v) {
    __hip_bfloat16 b = __float2bfloat16(v);
    return *(short*)&b;
}
__device__ __forceinline__ unsigned packbf2(float x, float y) {
    __hip_bfloat162 p = __float22bfloat162_rn(make_float2(x, y));
    return *(unsigned*)&p;
}

// ---------------- W transpose + bf16 convert (once per call) ----------------
// also zeroes the gcnt counter block (block 0) so no memset dispatch is needed
__global__ void wt_kernel(const float* __restrict__ W1, const float* __restrict__ W2,
                          short* __restrict__ WT1, short* __restrict__ WT2,
                          int* __restrict__ gcnt) {
    if (blockIdx.x == 0) {
        for (int i = threadIdx.x; i < 2 * NBUCK; i += 256) gcnt[i] = 0;
    }
    int idx = blockIdx.x * 256 + threadIdx.x;     // 0..32767
    int sel = idx >> 14;
    int li = idx & 16383;
    int n = li >> 7, k = li & 127;
    const float* src = sel ? W2 : W1;
    short* dst = sel ? WT2 : WT1;
    dst[li] = f2bf(src[k * 128 + n]);
}

// ---------------- Phase A: bucket partition, register-resident chunk ----------------
__launch_bounds__(256)
__global__ void binA_kernel(const int* __restrict__ nidx, const int* __restrict__ hidx,
                            int* __restrict__ gcnt_e, int* __restrict__ gcnt_n,
                            unsigned* __restrict__ bin_e, unsigned* __restrict__ bin_n) {
    __shared__ int hist_e[NBUCK], hist_n[NBUCK], base_e[NBUCK], base_n[NBUCK];
    int t = threadIdx.x;
    int items_h[16], items_n[16];
    int start = blockIdx.x * CHUNK;
#pragma unroll
    for (int k = 0; k < 16; ++k) {
        int i = start + t + k * 256;
        bool ok = i < N_INC;
        items_h[k] = ok ? hidx[i] : -1;
        items_n[k] = ok ? nidx[i] : -1;
    }
    for (int b = t; b < NBUCK; b += 256) { hist_e[b] = 0; hist_n[b] = 0; }
    __syncthreads();
#pragma unroll
    for (int k = 0; k < 16; ++k) {
        if (items_h[k] >= 0) {
            atomicAdd(&hist_e[items_h[k] >> 9], 1);
            atomicAdd(&hist_n[items_n[k] >> 9], 1);
        }
    }
    __syncthreads();
    for (int b = t; b < NBUCK; b += 256) {
        base_e[b] = atomicAdd(&gcnt_e[b], hist_e[b]);
        base_n[b] = atomicAdd(&gcnt_n[b], hist_n[b]);
        hist_e[b] = 0; hist_n[b] = 0;
    }
    __syncthreads();
#pragma unroll
    for (int k = 0; k < 16; ++k) {
        if (items_h[k] >= 0) {
            int h = items_h[k], n = items_n[k];
            int be = h >> 9, bn = n >> 9;
            int oe = base_e[be] + atomicAdd(&hist_e[be], 1);
            if (oe >= 0 && oe < CAP) bin_e[(size_t)be * CAP + oe] = ((unsigned)(h & 511) << 17) | (unsigned)n;
            int on = base_n[bn] + atomicAdd(&hist_n[bn], 1);
            if (on >= 0 && on < CAP) bin_n[(size_t)bn * CAP + on] = ((unsigned)(n & 511) << 17) | (unsigned)h;
        }
    }
}

// ---------------- Phase B: per-bucket counting sort, wave-shuffle scan ----------
__launch_bounds__(512)
__global__ void binB2_kernel(const int* __restrict__ gcnt_e, const unsigned* __restrict__ bin_e,
                             int* __restrict__ csr_e, int2* __restrict__ meta_e,
                             const int* __restrict__ gcnt_n, const unsigned* __restrict__ bin_n,
                             int* __restrict__ csr_n, int2* __restrict__ meta_n) {
    __shared__ int kc[B_KEYS];
    __shared__ int wsum[8];
    int b = blockIdx.x;
    const int* gcnt;  const unsigned* bin;  int* csr;  int2* meta;
    if (b < NBUCK) { gcnt = gcnt_e; bin = bin_e; csr = csr_e; meta = meta_e; }
    else { b -= NBUCK; gcnt = gcnt_n; bin = bin_n; csr = csr_n; meta = meta_n; }
    int t = threadIdx.x;
    int lane = t & 63, wv = t >> 6;
    int cnt = gcnt[b];
    if (cnt > CAP) cnt = CAP;
    kc[t] = 0;
    __syncthreads();
    const unsigned* items = bin + (size_t)b * CAP;
    for (int i = t; i < cnt; i += 512) atomicAdd(&kc[items[i] >> 17], 1);
    __syncthreads();
    int mycnt = kc[t];
    int v = mycnt;
#pragma unroll
    for (int off = 1; off < 64; off <<= 1) {
        int u = __shfl_up(v, off);
        if (lane >= off) v += u;
    }
    if (lane == 63) wsum[wv] = v;
    __syncthreads();
    int addp = 0;
#pragma unroll
    for (int w = 0; w < 7; ++w) addp += (w < wv) ? wsum[w] : 0;
    int incl = v + addp;
    int sstart = b * CAP + (incl - mycnt);   // exclusive start
    meta[b * B_KEYS + t] = make_int2(sstart, mycnt);
    kc[t] = sstart;
    __syncthreads();
    for (int i = t; i < cnt; i += 512) {
        unsigned it = items[i];
        int pos = atomicAdd(&kc[it >> 17], 1);
        csr[pos] = (int)(it & 0x1FFFFu);
    }
}

// ---------------- MFMA bf16 GEMM: planar output [8][N][16 feats] ----------------
// PLANAR=false: X is fp32 row-major [N][128]; PLANAR=true: X is bf16 planar.
template <bool PLANAR>
__launch_bounds__(256)
__global__ void gemm_mfma_kernel(const void* __restrict__ Xv, const short* __restrict__ WT,
                                 char* __restrict__ Y, int nrows) {
    __shared__ short lds_w[128 * LDA];   // W^T [n][k]; later reused for C staging
    int tid = threadIdx.x;
    int row0 = blockIdx.x * 64;

    {
        const uint4* w4 = (const uint4*)WT;
#pragma unroll
        for (int i = 0; i < 8; ++i) {
            int idx = tid + i * 256;          // 0..2047 = 128 rows x 16 uint4
            int n = idx >> 4, g = idx & 15;
            *(uint4*)(lds_w + n * LDA + g * 8) = w4[idx];
        }
    }

    int wv = tid >> 6, lane = tid & 63;
    int m = lane & 15, quad = lane >> 4;
    int row = row0 + wv * 16 + m;
    bool rowok = row < nrows;

    bf16x8 af[4];
    if constexpr (!PLANAR) {
        const float* xr = (const float*)Xv + (size_t)row * 128 + quad * 8;
#pragma unroll
        for (int k0 = 0; k0 < 4; ++k0) {
            float4 a0 = make_float4(0.f, 0.f, 0.f, 0.f), a1 = a0;
            if (rowok) {
                a0 = *(const float4*)(xr + k0 * 32);
                a1 = *(const float4*)(xr + k0 * 32 + 4);
            }
            bf16x8 f;
            f[0] = f2bf(a0.x); f[1] = f2bf(a0.y); f[2] = f2bf(a0.z); f[3] = f2bf(a0.w);
            f[4] = f2bf(a1.x); f[5] = f2bf(a1.y); f[6] = f2bf(a1.z); f[7] = f2bf(a1.w);
            af[k0] = f;
        }
    } else {
        const short* X = (const short*)Xv;
#pragma unroll
        for (int k0 = 0; k0 < 4; ++k0) {
            int p = k0 * 2 + (quad >> 1);
            bf16x8 f = {0, 0, 0, 0, 0, 0, 0, 0};
            if (rowok) f = *(const bf16x8*)(X + (size_t)p * PLANE_SHORTS + (size_t)row * 16 + (quad & 1) * 8);
            af[k0] = f;
        }
    }
    __syncthreads();   // W staged

    f32x4 zero = {0.f, 0.f, 0.f, 0.f};
    f32x4 acc[8];
#pragma unroll
    for (int t8 = 0; t8 < 8; ++t8) acc[t8] = zero;

#pragma unroll
    for (int t8 = 0; t8 < 8; ++t8) {
        const short* brow = lds_w + (t8 * 16 + m) * LDA + quad * 8;
#pragma unroll
        for (int k0 = 0; k0 < 4; ++k0) {
            bf16x8 bf = *(const bf16x8*)(brow + k0 * 32);
            acc[t8] = __builtin_amdgcn_mfma_f32_16x16x32_bf16(af[k0], bf, acc[t8], 0, 0, 0);
        }
    }

    __syncthreads();   // all W ds_reads done; reuse lds_w for C staging
    // C/D layout: col = lane&15, row = quad*4 + reg
#pragma unroll
    for (int t8 = 0; t8 < 8; ++t8) {
#pragma unroll
        for (int r = 0; r < 4; ++r) {
            int crow = wv * 16 + quad * 4 + r;
            int col = t8 * 16 + m;
            lds_w[crow * LDA + col] = f2bf(acc[t8][r]);
        }
    }
    __syncthreads();
    // planar store: per wave one plane, 64 rows x 2 halves = 1 KB contiguous
#pragma unroll
    for (int i = 0; i < 4; ++i) {
        int idx = tid + i * 256;              // 0..1023
        int slice = idx >> 7, j = idx & 127;  // j = row*2 + half
        int r = j >> 1, h = j & 1;
        if (row0 + r < nrows) {
            uint4 u = *(const uint4*)(lds_w + r * LDA + slice * 16 + h * 8);
            *(uint4*)(Y + (size_t)slice * PLANE_BYTES + (size_t)(row0 + r) * 32 + h * 16) = u;
        }
    }
}

// ---------------- sliced segment gather-sum ----------------
__device__ __forceinline__ void acc8_add(float* a, uint4 u) {
    a[0] += __uint_as_float(u.x << 16); a[1] += __uint_as_float(u.x & 0xFFFF0000u);
    a[2] += __uint_as_float(u.y << 16); a[3] += __uint_as_float(u.y & 0xFFFF0000u);
    a[4] += __uint_as_float(u.z << 16); a[5] += __uint_as_float(u.z & 0xFFFF0000u);
    a[6] += __uint_as_float(u.w << 16); a[7] += __uint_as_float(u.w & 0xFFFF0000u);
}
__device__ __forceinline__ void acc8_fma(float* a, uint4 u, float msk) {
    a[0] = fmaf(msk, __uint_as_float(u.x << 16), a[0]);
    a[1] = fmaf(msk, __uint_as_float(u.x & 0xFFFF0000u), a[1]);
    a[2] = fmaf(msk, __uint_as_float(u.y << 16), a[2]);
    a[3] = fmaf(msk, __uint_as_float(u.y & 0xFFFF0000u), a[3]);
    a[4] = fmaf(msk, __uint_as_float(u.z << 16), a[4]);
    a[5] = fmaf(msk, __uint_as_float(u.z & 0xFFFF0000u), a[5]);
    a[6] = fmaf(msk, __uint_as_float(u.w << 16), a[6]);
    a[7] = fmaf(msk, __uint_as_float(u.w & 0xFFFF0000u), a[7]);
}

// MODE 0: edge agg (scale only, planar bf16 out)
// MODE 1: node agg + bias + relu (planar bf16 out)
// MODE 2: node agg + bias + relu -> per-block column partials (dst = float*)
// slice = blockIdx & 7 -> XCD round-robin; each XCD gathers only from its own
// 3.2 MB plane (L2-resident). Round-2 lesson: indices must be CACHED loads
// (nt = 900-cyc HBM trip on the critical path, doubled the pass time); CSR
// indices are contiguous per segment so a 128 B L1 line feeds 4 inner steps.
template <int MODE>
__launch_bounds__(256)
__global__ void agg_planar_kernel(const char* __restrict__ src, const int2* __restrict__ meta,
                                  const int* __restrict__ col, const float* __restrict__ bias,
                                  char* __restrict__ dst) {
    int slice = blockIdx.x & 7;
    int g = blockIdx.x >> 3;
    int tid = threadIdx.x;
    int wid = tid >> 6, lane = tid & 63;
    int sub = lane >> 4;            // segment within wave (4 segs/wave)
    int slot = (lane >> 1) & 7;     // 8 gather rows in flight per segment
    int half = lane & 1;            // which 16 B half of the 32 B slice row
    const char* plane = src + (size_t)slice * PLANE_BYTES;

    float b8[8];
    if constexpr (MODE >= 1) {
        const float4* b4 = (const float4*)(bias + slice * 16 + half * 8);
        float4 lo = b4[0], hi = b4[1];
        b8[0] = lo.x; b8[1] = lo.y; b8[2] = lo.z; b8[3] = lo.w;
        b8[4] = hi.x; b8[5] = hi.y; b8[6] = hi.z; b8[7] = hi.w;
    }
    float psum[8];
    if constexpr (MODE == 2) {
#pragma unroll
        for (int i = 0; i < 8; ++i) psum[i] = 0.f;
    }

    for (int sb = g * 16 + wid * 4; sb < N_NODES; sb += GSLICE * 16) {
        int seg = sb + sub;
        int2 mt = meta[seg];
        int s = mt.x, cnt = mt.y;
        const int* cp = col + s + slot;
        float acc[8] = {0.f, 0.f, 0.f, 0.f, 0.f, 0.f, 0.f, 0.f};
        int nb = cnt >> 3;
        int bb = 0;
        // 2-deep pipeline: both index loads issue, then both gathers overlap
        for (; bb + 2 <= nb; bb += 2) {
            int ia = cp[bb * 8];
            int ib = cp[bb * 8 + 8];
            uint4 ua = *(const uint4*)(plane + (size_t)ia * 32 + half * 16);
            uint4 ub = *(const uint4*)(plane + (size_t)ib * 32 + half * 16);
            acc8_add(acc, ua);
            acc8_add(acc, ub);
        }
        if (bb < nb) {
            int ia = cp[bb * 8];
            uint4 ua = *(const uint4*)(plane + (size_t)ia * 32 + half * 16);
            acc8_add(acc, ua);
        }
        if (cnt & 7) {                       // masked tail batch
            int j = nb * 8 + slot;
            float msk = (j < cnt) ? 1.0f : 0.0f;
            int jc = (j < cnt) ? j : 0;
            int ia = col[s + jc];
            uint4 u = *(const uint4*)(plane + (size_t)ia * 32 + half * 16);
            acc8_fma(acc, u, msk);
        }
        // reduce across the 8 row slots (lane bits 1..3)
#pragma unroll
        for (int i = 0; i < 8; ++i) {
            acc[i] += __shfl_xor(acc[i], 2);
            acc[i] += __shfl_xor(acc[i], 4);
            acc[i] += __shfl_xor(acc[i], 8);
        }
        if (slot == 0) {
            float sc = cnt ? 1.0f / (float)cnt : 0.0f;
            if constexpr (MODE == 0) {
                uint4 o;
                o.x = packbf2(acc[0] * sc, acc[1] * sc);
                o.y = packbf2(acc[2] * sc, acc[3] * sc);
                o.z = packbf2(acc[4] * sc, acc[5] * sc);
                o.w = packbf2(acc[6] * sc, acc[7] * sc);
                *(uint4*)(dst + (size_t)slice * PLANE_BYTES + (size_t)seg * 32 + half * 16) = o;
            } else if constexpr (MODE == 1) {
                uint4 o;
                o.x = packbf2(fmaxf(fmaf(acc[0], sc, b8[0]), 0.f), fmaxf(fmaf(acc[1], sc, b8[1]), 0.f));
                o.y = packbf2(fmaxf(fmaf(acc[2], sc, b8[2]), 0.f), fmaxf(fmaf(acc[3], sc, b8[3]), 0.f));
                o.z = packbf2(fmaxf(fmaf(acc[4], sc, b8[4]), 0.f), fmaxf(fmaf(acc[5], sc, b8[5]), 0.f));
                o.w = packbf2(fmaxf(fmaf(acc[6], sc, b8[6]), 0.f), fmaxf(fmaf(acc[7], sc, b8[7]), 0.f));
                *(uint4*)(dst + (size_t)slice * PLANE_BYTES + (size_t)seg * 32 + half * 16) = o;
            } else {
#pragma unroll
                for (int i = 0; i < 8; ++i)
                    psum[i] += fmaxf(fmaf(acc[i], sc, b8[i]), 0.f);
            }
        }
    }
    if constexpr (MODE == 2) {
        __shared__ float sp[16];
        if (tid < 16) sp[tid] = 0.f;
        __syncthreads();
        if (slot == 0) {
#pragma unroll
            for (int i = 0; i < 8; ++i) atomicAdd(&sp[half * 8 + i], psum[i]);
        }
        __syncthreads();
        if (tid < 16)
            ((float*)dst)[((size_t)slice * GSLICE + g) * 16 + tid] = sp[tid];
    }
}

// ---------------- mean: reduce per-block partials [8][GSLICE][16] ----------------
__launch_bounds__(256)
__global__ void mean_kernel(const float* __restrict__ partials, float* __restrict__ out) {
    __shared__ float sd[256];
    int f = blockIdx.x;               // 0..127
    int slice = f >> 4, w = f & 15;
    float s = 0.f;
    for (int g = threadIdx.x; g < GSLICE; g += 256)
        s += partials[((size_t)slice * GSLICE + g) * 16 + w];
    sd[threadIdx.x] = s;
    __syncthreads();
#pragma unroll
    for (int o = 128; o > 0; o >>= 1) {
        if (threadIdx.x < o) sd[threadIdx.x] += sd[threadIdx.x + o];
        __syncthreads();
    }
    if (threadIdx.x == 0) out[f] = sd[0] * (1.0f / (float)N_NODES);
}

// ---------------- launch ----------------
extern "C" void kernel_launch(void* const* d_in, const int* in_sizes, int n_in,
                              void* d_out, int out_size, void* d_ws, size_t ws_size,
                              hipStream_t stream) {
    const float* x  = (const float*)d_in[0];
    const int*   ei = (const int*)d_in[1];
    const float* w1 = (const float*)d_in[2];
    const float* b1 = (const float*)d_in[3];
    const float* w2 = (const float*)d_in[4];
    const float* b2 = (const float*)d_in[5];
    float* out = (float*)d_out;
    const int* nidx = ei;
    const int* hidx = ei + N_INC;

    char* wsp = (char*)d_ws;
    size_t off = 0;
    auto alloc = [&](size_t bytes) -> void* {
        void* p = wsp + off;
        off += (bytes + 255) & ~(size_t)255;
        return p;
    };

    char* B0         = (char*)alloc((size_t)N_NODES * 128 * 2);   // planar bf16
    char* B1         = (char*)alloc((size_t)N_NODES * 128 * 2);   // planar bf16
    unsigned* bin_e  = (unsigned*)alloc((size_t)NBUCK * CAP * 4);
    unsigned* bin_n  = (unsigned*)alloc((size_t)NBUCK * CAP * 4);
    int* csr_e       = (int*)alloc((size_t)NBUCK * CAP * 4);
    int* csr_n       = (int*)alloc((size_t)NBUCK * CAP * 4);
    float* partials  = (float*)alloc((size_t)NSLICE * GSLICE * 16 * 4);
    int2* meta_e     = (int2*)alloc((size_t)NBUCK * B_KEYS * 8);
    int2* meta_n     = (int2*)alloc((size_t)NBUCK * B_KEYS * 8);
    short* WT1       = (short*)alloc((size_t)128 * 128 * 2);
    short* WT2       = (short*)alloc((size_t)128 * 128 * 2);
    int* gcnt        = (int*)alloc((size_t)2 * NBUCK * 4);
    int* gcnt_e = gcnt;
    int* gcnt_n = gcnt + NBUCK;

    wt_kernel<<<128, 256, 0, stream>>>(w1, w2, WT1, WT2, gcnt);
    binA_kernel<<<NBLKA, 256, 0, stream>>>(nidx, hidx, gcnt_e, gcnt_n, bin_e, bin_n);
    binB2_kernel<<<2 * NBUCK, 512, 0, stream>>>(gcnt_e, bin_e, csr_e, meta_e,
                                                gcnt_n, bin_n, csr_n, meta_n);

    int gGemm = (N_NODES + 63) / 64;
    int gAgg = NSLICE * GSLICE;

    // layer 1
    gemm_mfma_kernel<false><<<gGemm, 256, 0, stream>>>(x, WT1, B0, N_NODES);
    agg_planar_kernel<0><<<gAgg, 256, 0, stream>>>(B0, meta_e, csr_e, nullptr, B1);
    agg_planar_kernel<1><<<gAgg, 256, 0, stream>>>(B1, meta_n, csr_n, b1, B0);
    // layer 2
    gemm_mfma_kernel<true><<<gGemm, 256, 0, stream>>>(B0, WT2, B1, N_NODES);
    agg_planar_kernel<0><<<gAgg, 256, 0, stream>>>(B1, meta_e, csr_e, nullptr, B0);
    agg_planar_kernel<2><<<gAgg, 256, 0, stream>>>(B0, meta_n, csr_n, b2, (char*)partials);
    mean_kernel<<<128, 256, 0, stream>>>(partials, out);
}